// Round 4
// baseline (165.732 us; speedup 1.0000x reference)
//
#include <hip/hip_runtime.h>

#define LRELU(x) ((x) > 0.f ? (x) : 0.01f * (x))

// ws layout (float offsets)
#define H2_OFF    0          // [8][16][512]
#define T1_OFF    65536      // [8][512]
#define T2_OFF    69632      // [8][512]
#define PK_OFF    73728      // [8][2048]
#define PB_OFF    90112      // [8][512]
#define D_OFF     94208      // [8][9][2048]

// ---------------- kA: h (1x1 conv + lrelu) and pooled-style stage 1 ----------------
__global__ __launch_bounds__(256) void kA(const float* __restrict__ style,
    const float* __restrict__ dw1_w, const float* __restrict__ dw1_b,
    const float* __restrict__ pk1_w, const float* __restrict__ pk1_b,
    const float* __restrict__ pb1_w, const float* __restrict__ pb1_b,
    float* __restrict__ h2, float* __restrict__ t1, float* __restrict__ t2) {
  int b = blockIdx.x;
  __shared__ float s[512];
  if (b < 256) {
    int n = b >> 5, pix = (b >> 1) & 15, half = b & 1;
    const float* sp = style + n * 8192 + pix;
    for (int i = threadIdx.x; i < 512; i += 256) s[i] = sp[i * 16];
    __syncthreads();
    int co = half * 256 + threadIdx.x;
    const float4* wr = (const float4*)(dw1_w + co * 512);
    float acc = dw1_b[co];
#pragma unroll 8
    for (int k = 0; k < 128; ++k) {
      float4 wv = wr[k];
      acc += wv.x * s[4*k] + wv.y * s[4*k+1] + wv.z * s[4*k+2] + wv.w * s[4*k+3];
    }
    h2[n * 8192 + pix * 512 + co] = LRELU(acc);
  } else {
    int idx = b - 256; int n = idx >> 1, which = idx & 1;
    for (int ci = threadIdx.x; ci < 512; ci += 256) {
      const float4* r4 = (const float4*)(style + n * 8192 + ci * 16);
      float4 a = r4[0], bb = r4[1], c = r4[2], d = r4[3];
      s[ci] = (a.x+a.y+a.z+a.w + bb.x+bb.y+bb.z+bb.w + c.x+c.y+c.z+c.w + d.x+d.y+d.z+d.w) * (1.f/16.f);
    }
    __syncthreads();
    const float* w  = which ? pb1_w : pk1_w;
    const float* bv = which ? pb1_b : pk1_b;
    float* o = which ? t2 : t1;
    for (int co = threadIdx.x; co < 512; co += 256) {
      const float4* wr = (const float4*)(w + co * 512);
      float acc = bv[co];
#pragma unroll 8
      for (int k = 0; k < 128; ++k) {
        float4 wv = wr[k];
        acc += wv.x * s[4*k] + wv.y * s[4*k+1] + wv.z * s[4*k+2] + wv.w * s[4*k+3];
      }
      o[n * 512 + co] = LRELU(acc);
    }
  }
}

// ---------------- kB: split-K dw2 matmul (all n per block) + pk2/pb2 ----------------
__global__ __launch_bounds__(256) void kB(const float* __restrict__ h2,
    const float* __restrict__ dw2_w,
    const float* __restrict__ t1, const float* __restrict__ t2,
    const float* __restrict__ pk2_w, const float* __restrict__ pk2_b,
    const float* __restrict__ pb2_w, const float* __restrict__ pb2_b,
    float* __restrict__ D, float* __restrict__ pk, float* __restrict__ pb) {
  __shared__ float smem[4608];  // k5: A[8][9][64]; k4: s[512]
  int b = blockIdx.x;
  if (b < 256) {
    int bo = b & 7, kc = b >> 3;  // o2 tile of 256, k chunk of 64
    float* A = smem;
    for (int idx = threadIdx.x; idx < 8 * 9 * 64; idx += 256) {
      int kk = idx & 63; int p = (idx >> 6) % 9; int n = idx / (9 * 64);
      int cik = kc * 64 + kk; int ci = cik >> 2; int kyx = cik & 3;
      int ky = kyx >> 1, kx = kyx & 1;
      int pix = (p / 3 + ky) * 4 + (p % 3 + kx);
      A[idx] = h2[n * 8192 + pix * 512 + ci];
    }
    __syncthreads();
    int o2 = bo * 256 + threadIdx.x;
    const float4* wr = (const float4*)(dw2_w + o2 * 2048 + kc * 64);
    float acc[8][9];
#pragma unroll
    for (int n = 0; n < 8; ++n)
#pragma unroll
      for (int p = 0; p < 9; ++p) acc[n][p] = 0.f;
#pragma unroll 1
    for (int k = 0; k < 16; ++k) {
      float4 wv = wr[k];
#pragma unroll
      for (int n = 0; n < 8; ++n) {
#pragma unroll
        for (int p = 0; p < 9; ++p) {
          float4 a = *(const float4*)&A[(n * 9 + p) * 64 + 4 * k];
          acc[n][p] += wv.x * a.x + wv.y * a.y + wv.z * a.z + wv.w * a.w;
        }
      }
    }
#pragma unroll
    for (int n = 0; n < 8; ++n)
#pragma unroll
      for (int p = 0; p < 9; ++p)
        atomicAdd(&D[(n * 9 + p) * 2048 + o2], acc[n][p]);
  } else {
    int idx = b - 256;  // 0..79
    int n = idx / 10; int tile = idx % 10;
    bool isPb = tile >= 8;
    float* s = smem;
    const float* src = (isPb ? t2 : t1) + n * 512;
    for (int i = threadIdx.x; i < 512; i += 256) s[i] = src[i];
    __syncthreads();
    int o = (isPb ? tile - 8 : tile) * 256 + threadIdx.x;
    const float* w = isPb ? pb2_w : pk2_w;
    float acc = (isPb ? pb2_b : pk2_b)[o];
    const float4* wr = (const float4*)(w + o * 512);
#pragma unroll 8
    for (int k = 0; k < 128; ++k) {
      float4 wv = wr[k];
      acc += wv.x * s[4*k] + wv.y * s[4*k+1] + wv.z * s[4*k+2] + wv.w * s[4*k+3];
    }
    if (isPb) pb[n * 512 + o] = acc; else pk[n * 2048 + o] = acc;
  }
}

// ---------------- kC: inline weff + fused grouped 3x3 conv ----------------
// block = (n, Q, 32-row half); thread = (row r 0..31, col-eighth e 0..7)
// each thread: 4 out-ch x 8 px in regs
__global__ __launch_bounds__(256) void kC(const float* __restrict__ x,
    const float* __restrict__ D, const float* __restrict__ pk,
    const float* __restrict__ dw2_b, const float* __restrict__ pb,
    float* __restrict__ out) {
  int b = blockIdx.x; int rt = b & 1; int Q = (b >> 1) & 127; int n = b >> 8;
  __shared__ float xs[4][34][76];  // [i][row][k]; k = x+4; stride 76 => 2-way banks max
  __shared__ float wsm[144];       // [ky][i][kx][o]
  __shared__ float bs4[4];
  int tid = threadIdx.x;
  // inline weff: wsm[(ky*4+i)*12 + kx*4 + o] = sum_j pk[...]*(D[...]+b2[...])
  if (tid < 144) {
    int o = tid & 3; int r2 = tid >> 2; int kx = r2 % 3; int r3 = r2 / 3;
    int i = r3 & 3; int ky = r3 >> 2; int p = ky * 3 + kx;
    const float* Dp  = D + (n * 9 + p) * 2048 + 16 * Q;
    const float* pkp = pk + n * 2048 + 16 * Q + 4 * o;
    const float* bp  = dw2_b + 16 * Q;
    float sum = 0.f;
#pragma unroll
    for (int j = 0; j < 4; ++j) sum += pkp[j] * (Dp[4 * j + i] + bp[4 * j + i]);
    wsm[(ky * 4 + i) * 12 + kx * 4 + o] = sum;
  }
  if (tid >= 144 && tid < 148) bs4[tid - 144] = pb[n * 512 + Q * 4 + (tid - 144)];
  // stage x tile (32 rows + halo) with reflect padding
  const float* base = x + (size_t)(n * 512 + Q * 4) * 4096;
  for (int idx = tid; idx < 4 * 34 * 18; idx += 256) {
    int c = idx % 18; int t2 = idx / 18; int rr = t2 % 34; int ch = t2 / 34;
    int gy = rt * 32 + rr - 1; gy = gy < 0 ? 1 : (gy > 63 ? 62 : gy);
    const float* src = base + ch * 4096 + gy * 64;
    if (c == 0)       xs[ch][rr][3]  = src[1];    // x=-1 -> reflect 1
    else if (c == 17) xs[ch][rr][68] = src[62];   // x=64 -> reflect 62
    else *(float4*)&xs[ch][rr][4 * c] = *(const float4*)(src + 4 * (c - 1));
  }
  __syncthreads();
  int r = tid >> 3, e = tid & 7;
  float acc[4][8];
#pragma unroll
  for (int o = 0; o < 4; ++o)
#pragma unroll
    for (int px = 0; px < 8; ++px) acc[o][px] = bs4[o];
#pragma unroll
  for (int ky = 0; ky < 3; ++ky) {
#pragma unroll
    for (int i = 0; i < 4; ++i) {
      const float4* vp = (const float4*)&xs[i][r + ky][8 * e];
      float4 v0 = vp[0], v1 = vp[1], v2 = vp[2], v3 = vp[3];
      float v[16];
      v[0]=v0.x; v[1]=v0.y; v[2]=v0.z; v[3]=v0.w;
      v[4]=v1.x; v[5]=v1.y; v[6]=v1.z; v[7]=v1.w;
      v[8]=v2.x; v[9]=v2.y; v[10]=v2.z; v[11]=v2.w;
      v[12]=v3.x; v[13]=v3.y; v[14]=v3.z; v[15]=v3.w;
      const float* wp = &wsm[(ky * 4 + i) * 12];
#pragma unroll
      for (int kx = 0; kx < 3; ++kx) {
        float w0 = wp[kx*4+0], w1 = wp[kx*4+1], w2 = wp[kx*4+2], w3 = wp[kx*4+3];
#pragma unroll
        for (int px = 0; px < 8; ++px) {
          float xv = v[3 + px + kx];
          acc[0][px] += w0 * xv;
          acc[1][px] += w1 * xv;
          acc[2][px] += w2 * xv;
          acc[3][px] += w3 * xv;
        }
      }
    }
  }
  int gy = rt * 32 + r;
#pragma unroll
  for (int o = 0; o < 4; ++o) {
    float* op = out + (((size_t)(n * 512 + Q * 4 + o)) * 64 + gy) * 64 + 8 * e;
    float4 s0; s0.x = acc[o][0]; s0.y = acc[o][1]; s0.z = acc[o][2]; s0.w = acc[o][3];
    float4 s1; s1.x = acc[o][4]; s1.y = acc[o][5]; s1.z = acc[o][6]; s1.w = acc[o][7];
    *(float4*)op = s0;
    *(float4*)(op + 4) = s1;
  }
}

extern "C" void kernel_launch(void* const* d_in, const int* in_sizes, int n_in,
                              void* d_out, int out_size, void* d_ws, size_t ws_size,
                              hipStream_t stream) {
  const float* style = (const float*)d_in[0];
  const float* pred  = (const float*)d_in[1];
  const float* dw1_w = (const float*)d_in[2];
  const float* dw1_b = (const float*)d_in[3];
  const float* dw2_w = (const float*)d_in[4];
  const float* dw2_b = (const float*)d_in[5];
  const float* pk1_w = (const float*)d_in[6];
  const float* pk1_b = (const float*)d_in[7];
  const float* pk2_w = (const float*)d_in[8];
  const float* pk2_b = (const float*)d_in[9];
  const float* pb1_w = (const float*)d_in[10];
  const float* pb1_b = (const float*)d_in[11];
  const float* pb2_w = (const float*)d_in[12];
  const float* pb2_b = (const float*)d_in[13];
  float* ws = (float*)d_ws;
  float* h2 = ws + H2_OFF;
  float* t1 = ws + T1_OFF;
  float* t2 = ws + T2_OFF;
  float* pk = ws + PK_OFF;
  float* pb = ws + PB_OFF;
  float* D  = ws + D_OFF;
  float* out = (float*)d_out;

  hipMemsetAsync(D, 0, (size_t)8 * 9 * 2048 * sizeof(float), stream);
  kA<<<272, 256, 0, stream>>>(style, dw1_w, dw1_b, pk1_w, pk1_b, pb1_w, pb1_b, h2, t1, t2);
  kB<<<336, 256, 0, stream>>>(h2, dw2_w, t1, t2, pk2_w, pk2_b, pb2_w, pb2_b, D, pk, pb);
  kC<<<2048, 256, 0, stream>>>(pred, D, pk, dw2_b, pb, out);
}

// Round 5
// 137.780 us; speedup vs baseline: 1.2029x; 1.2029x over previous
//
#include <hip/hip_runtime.h>

#define LRELU(x) ((x) > 0.f ? (x) : 0.01f * (x))

// ws layout (float offsets)
#define H2_OFF    0          // [8][16][512]
#define T1_OFF    65536      // [8][512]
#define T2_OFF    69632      // [8][512]
#define PK_OFF    73728      // [8][2048]
#define PB_OFF    90112      // [8][512]
#define D_OFF     94208      // [8][9][2048]
#define WB_OFF    241664     // [8][128][160]  (144 weff + 4 pb + 12 pad)

// ---------------- kA: h (1x1 conv + lrelu) and pooled-style stage 1 ----------------
__global__ __launch_bounds__(256) void kA(const float* __restrict__ style,
    const float* __restrict__ dw1_w, const float* __restrict__ dw1_b,
    const float* __restrict__ pk1_w, const float* __restrict__ pk1_b,
    const float* __restrict__ pb1_w, const float* __restrict__ pb1_b,
    float* __restrict__ h2, float* __restrict__ t1, float* __restrict__ t2) {
  int b = blockIdx.x;
  __shared__ float s[512];
  if (b < 256) {
    int n = b >> 5, pix = (b >> 1) & 15, half = b & 1;
    const float* sp = style + n * 8192 + pix;
    for (int i = threadIdx.x; i < 512; i += 256) s[i] = sp[i * 16];
    __syncthreads();
    int co = half * 256 + threadIdx.x;
    const float4* wr = (const float4*)(dw1_w + co * 512);
    float acc = dw1_b[co];
#pragma unroll 8
    for (int k = 0; k < 128; ++k) {
      float4 wv = wr[k];
      acc += wv.x * s[4*k] + wv.y * s[4*k+1] + wv.z * s[4*k+2] + wv.w * s[4*k+3];
    }
    h2[n * 8192 + pix * 512 + co] = LRELU(acc);
  } else {
    int idx = b - 256; int n = idx >> 1, which = idx & 1;
    for (int ci = threadIdx.x; ci < 512; ci += 256) {
      const float4* r4 = (const float4*)(style + n * 8192 + ci * 16);
      float4 a = r4[0], bb = r4[1], c = r4[2], d = r4[3];
      s[ci] = (a.x+a.y+a.z+a.w + bb.x+bb.y+bb.z+bb.w + c.x+c.y+c.z+c.w + d.x+d.y+d.z+d.w) * (1.f/16.f);
    }
    __syncthreads();
    const float* w  = which ? pb1_w : pk1_w;
    const float* bv = which ? pb1_b : pk1_b;
    float* o = which ? t2 : t1;
    for (int co = threadIdx.x; co < 512; co += 256) {
      const float4* wr = (const float4*)(w + co * 512);
      float acc = bv[co];
#pragma unroll 8
      for (int k = 0; k < 128; ++k) {
        float4 wv = wr[k];
        acc += wv.x * s[4*k] + wv.y * s[4*k+1] + wv.z * s[4*k+2] + wv.w * s[4*k+3];
      }
      o[n * 512 + co] = LRELU(acc);
    }
  }
}

// ---------------- kB: split-K dw2 matmul (all n per block) + pk2/pb2 ----------------
__global__ __launch_bounds__(256) void kB(const float* __restrict__ h2,
    const float* __restrict__ dw2_w,
    const float* __restrict__ t1, const float* __restrict__ t2,
    const float* __restrict__ pk2_w, const float* __restrict__ pk2_b,
    const float* __restrict__ pb2_w, const float* __restrict__ pb2_b,
    float* __restrict__ D, float* __restrict__ pk, float* __restrict__ pb) {
  __shared__ float smem[4608];
  int b = blockIdx.x;
  if (b < 256) {
    int bo = b & 7, kc = b >> 3;
    float* A = smem;
    for (int idx = threadIdx.x; idx < 8 * 9 * 64; idx += 256) {
      int kk = idx & 63; int p = (idx >> 6) % 9; int n = idx / (9 * 64);
      int cik = kc * 64 + kk; int ci = cik >> 2; int kyx = cik & 3;
      int ky = kyx >> 1, kx = kyx & 1;
      int pix = (p / 3 + ky) * 4 + (p % 3 + kx);
      A[idx] = h2[n * 8192 + pix * 512 + ci];
    }
    __syncthreads();
    int o2 = bo * 256 + threadIdx.x;
    const float4* wr = (const float4*)(dw2_w + o2 * 2048 + kc * 64);
    float acc[8][9];
#pragma unroll
    for (int n = 0; n < 8; ++n)
#pragma unroll
      for (int p = 0; p < 9; ++p) acc[n][p] = 0.f;
#pragma unroll 1
    for (int k = 0; k < 16; ++k) {
      float4 wv = wr[k];
#pragma unroll
      for (int n = 0; n < 8; ++n) {
#pragma unroll
        for (int p = 0; p < 9; ++p) {
          float4 a = *(const float4*)&A[(n * 9 + p) * 64 + 4 * k];
          acc[n][p] += wv.x * a.x + wv.y * a.y + wv.z * a.z + wv.w * a.w;
        }
      }
    }
#pragma unroll
    for (int n = 0; n < 8; ++n)
#pragma unroll
      for (int p = 0; p < 9; ++p)
        atomicAdd(&D[(n * 9 + p) * 2048 + o2], acc[n][p]);
  } else {
    int idx = b - 256;
    int n = idx / 10; int tile = idx % 10;
    bool isPb = tile >= 8;
    float* s = smem;
    const float* src = (isPb ? t2 : t1) + n * 512;
    for (int i = threadIdx.x; i < 512; i += 256) s[i] = src[i];
    __syncthreads();
    int o = (isPb ? tile - 8 : tile) * 256 + threadIdx.x;
    const float* w = isPb ? pb2_w : pk2_w;
    float acc = (isPb ? pb2_b : pk2_b)[o];
    const float4* wr = (const float4*)(w + o * 512);
#pragma unroll 8
    for (int k = 0; k < 128; ++k) {
      float4 wv = wr[k];
      acc += wv.x * s[4*k] + wv.y * s[4*k+1] + wv.z * s[4*k+2] + wv.w * s[4*k+3];
    }
    if (isPb) pb[n * 512 + o] = acc; else pk[n * 2048 + o] = acc;
  }
}

// ---------------- kW: weff + pb -> wbuf[n][Q][160] ----------------
// wbuf layout: t = ((ky*4+i)*3+kx)*4+o for t<144; t=144..147: pb; 148..159: pad
__global__ __launch_bounds__(256) void kW(const float* __restrict__ D,
    const float* __restrict__ pk, const float* __restrict__ dw2_b,
    const float* __restrict__ pb, float* __restrict__ wbuf) {
  int idx = blockIdx.x * 256 + threadIdx.x;
  if (idx >= 8 * 128 * 160) return;
  int t = idx % 160; int Qn = idx / 160; int Q = Qn & 127; int n = Qn >> 7;
  if (t >= 144) {
    wbuf[idx] = (t < 148) ? pb[n * 512 + Q * 4 + (t - 144)] : 0.f;
    return;
  }
  int o = t & 3; int u = t >> 2; int kx = u % 3; int v = u / 3;
  int i = v & 3; int ky = v >> 2; int p = ky * 3 + kx;
  const float* Dp  = D + (n * 9 + p) * 2048 + 16 * Q;
  const float* pkp = pk + n * 2048 + 16 * Q + 4 * o;
  const float* bp  = dw2_b + 16 * Q;
  float sum = 0.f;
#pragma unroll
  for (int j = 0; j < 4; ++j) sum += pkp[j] * (Dp[4 * j + i] + bp[4 * j + i]);
  wbuf[idx] = sum;
}

// ---------------- kC: fused grouped 3x3 conv, scalar-loaded weights ----------------
// block = (n, Q, 16-row quarter); thread = (r 0..15, e 0..15): 4 o x 4 px
__global__ __launch_bounds__(256) void kC(const float* __restrict__ x,
    const float* __restrict__ wbuf, float* __restrict__ out) {
  int b = blockIdx.x; int rt = b & 3; int Q = (b >> 2) & 127; int n = b >> 9;
  __shared__ float xs[4][18][80];  // col = 4 + x; halos at col 3 (x=-1), 68 (x=64)
  const float* wb = wbuf + (size_t)(n * 128 + Q) * 160;  // block-uniform -> s_load
  const float* base = x + (size_t)(n * 512 + Q * 4) * 4096;
  // interior: 4ch x 18rr x 16 float4
  for (int idx = threadIdx.x; idx < 1152; idx += 256) {
    int c4 = idx & 15; int rr = (idx >> 4) % 18; int ch = idx / 288;
    int gy = rt * 16 + rr - 1; gy = gy < 0 ? 1 : (gy > 63 ? 62 : gy);
    *(float4*)&xs[ch][rr][4 + 4 * c4] = *(const float4*)(base + ch * 4096 + gy * 64 + 4 * c4);
  }
  // halos: 4ch x 18rr x 2
  if (threadIdx.x < 144) {
    int idx = threadIdx.x;
    int side = idx & 1; int rr = (idx >> 1) % 18; int ch = idx / 36;
    int gy = rt * 16 + rr - 1; gy = gy < 0 ? 1 : (gy > 63 ? 62 : gy);
    xs[ch][rr][side ? 68 : 3] = base[ch * 4096 + gy * 64 + (side ? 62 : 1)];
  }
  __syncthreads();
  int r = threadIdx.x >> 4, e = threadIdx.x & 15;
  float acc[4][4];  // [o][px]
#pragma unroll
  for (int o = 0; o < 4; ++o) {
    float bv = wb[144 + o];
#pragma unroll
    for (int px = 0; px < 4; ++px) acc[o][px] = bv;
  }
#pragma unroll
  for (int ky = 0; ky < 3; ++ky) {
#pragma unroll
    for (int i = 0; i < 4; ++i) {
      const float* rp = &xs[i][r + ky][4 * e];
      float4 v0 = *(const float4*)rp;         // cols 4e..4e+3
      float4 v1 = *(const float4*)(rp + 4);   // cols 4e+4..4e+7
      float2 v2 = *(const float2*)(rp + 8);   // cols 4e+8..4e+9
      float vv[10];
      vv[0]=v0.x; vv[1]=v0.y; vv[2]=v0.z; vv[3]=v0.w;
      vv[4]=v1.x; vv[5]=v1.y; vv[6]=v1.z; vv[7]=v1.w;
      vv[8]=v2.x; vv[9]=v2.y;
      // needed: col(px,kx) = 4e+3+px+kx -> vv[3+px+kx]
#pragma unroll
      for (int kx = 0; kx < 3; ++kx) {
        float w0 = wb[((ky * 4 + i) * 3 + kx) * 4 + 0];
        float w1 = wb[((ky * 4 + i) * 3 + kx) * 4 + 1];
        float w2 = wb[((ky * 4 + i) * 3 + kx) * 4 + 2];
        float w3 = wb[((ky * 4 + i) * 3 + kx) * 4 + 3];
#pragma unroll
        for (int px = 0; px < 4; ++px) {
          float xv = vv[3 + px + kx];
          acc[0][px] += w0 * xv;
          acc[1][px] += w1 * xv;
          acc[2][px] += w2 * xv;
          acc[3][px] += w3 * xv;
        }
      }
    }
  }
  int gy = rt * 16 + r;
#pragma unroll
  for (int o = 0; o < 4; ++o) {
    float4 st; st.x = acc[o][0]; st.y = acc[o][1]; st.z = acc[o][2]; st.w = acc[o][3];
    *(float4*)&out[(((size_t)(n * 512 + Q * 4 + o)) * 64 + gy) * 64 + 4 * e] = st;
  }
}

extern "C" void kernel_launch(void* const* d_in, const int* in_sizes, int n_in,
                              void* d_out, int out_size, void* d_ws, size_t ws_size,
                              hipStream_t stream) {
  const float* style = (const float*)d_in[0];
  const float* pred  = (const float*)d_in[1];
  const float* dw1_w = (const float*)d_in[2];
  const float* dw1_b = (const float*)d_in[3];
  const float* dw2_w = (const float*)d_in[4];
  const float* dw2_b = (const float*)d_in[5];
  const float* pk1_w = (const float*)d_in[6];
  const float* pk1_b = (const float*)d_in[7];
  const float* pk2_w = (const float*)d_in[8];
  const float* pk2_b = (const float*)d_in[9];
  const float* pb1_w = (const float*)d_in[10];
  const float* pb1_b = (const float*)d_in[11];
  const float* pb2_w = (const float*)d_in[12];
  const float* pb2_b = (const float*)d_in[13];
  float* ws = (float*)d_ws;
  float* h2 = ws + H2_OFF;
  float* t1 = ws + T1_OFF;
  float* t2 = ws + T2_OFF;
  float* pk = ws + PK_OFF;
  float* pb = ws + PB_OFF;
  float* D  = ws + D_OFF;
  float* wb = ws + WB_OFF;
  float* out = (float*)d_out;

  hipMemsetAsync(D, 0, (size_t)8 * 9 * 2048 * sizeof(float), stream);
  kA<<<272, 256, 0, stream>>>(style, dw1_w, dw1_b, pk1_w, pk1_b, pb1_w, pb1_b, h2, t1, t2);
  kB<<<336, 256, 0, stream>>>(h2, dw2_w, t1, t2, pk2_w, pk2_b, pb2_w, pb2_b, D, pk, pb);
  kW<<<640, 256, 0, stream>>>(D, pk, dw2_b, pb, wb);
  kC<<<4096, 256, 0, stream>>>(pred, wb, out);
}

// Round 6
// 126.994 us; speedup vs baseline: 1.3050x; 1.0849x over previous
//
#include <hip/hip_runtime.h>

#define LRELU(x) ((x) > 0.f ? (x) : 0.01f * (x))

// ws layout (float offsets)
#define H2_OFF    0          // [8][16][512]
#define T1_OFF    65536      // [8][512]
#define T2_OFF    69632      // [8][512]
#define PK_OFF    73728      // [8][2048]
#define PB_OFF    90112      // [8][512]
#define D_OFF     94208      // [8][9][2048]
#define WB_OFF    241664     // [8][128][160]  (144 weff + 4 pb + 12 pad)

// ---------------- kA: h (1x1 conv + lrelu) and pooled-style stage 1 ----------------
__global__ __launch_bounds__(256) void kA(const float* __restrict__ style,
    const float* __restrict__ dw1_w, const float* __restrict__ dw1_b,
    const float* __restrict__ pk1_w, const float* __restrict__ pk1_b,
    const float* __restrict__ pb1_w, const float* __restrict__ pb1_b,
    float* __restrict__ h2, float* __restrict__ t1, float* __restrict__ t2) {
  int b = blockIdx.x;
  __shared__ float s[512];
  if (b < 256) {
    int n = b >> 5, pix = (b >> 1) & 15, half = b & 1;
    const float* sp = style + n * 8192 + pix;
    for (int i = threadIdx.x; i < 512; i += 256) s[i] = sp[i * 16];
    __syncthreads();
    int co = half * 256 + threadIdx.x;
    const float4* wr = (const float4*)(dw1_w + co * 512);
    float acc = dw1_b[co];
#pragma unroll 8
    for (int k = 0; k < 128; ++k) {
      float4 wv = wr[k];
      acc += wv.x * s[4*k] + wv.y * s[4*k+1] + wv.z * s[4*k+2] + wv.w * s[4*k+3];
    }
    h2[n * 8192 + pix * 512 + co] = LRELU(acc);
  } else {
    int idx = b - 256; int n = idx >> 1, which = idx & 1;
    for (int ci = threadIdx.x; ci < 512; ci += 256) {
      const float4* r4 = (const float4*)(style + n * 8192 + ci * 16);
      float4 a = r4[0], bb = r4[1], c = r4[2], d = r4[3];
      s[ci] = (a.x+a.y+a.z+a.w + bb.x+bb.y+bb.z+bb.w + c.x+c.y+c.z+c.w + d.x+d.y+d.z+d.w) * (1.f/16.f);
    }
    __syncthreads();
    const float* w  = which ? pb1_w : pk1_w;
    const float* bv = which ? pb1_b : pk1_b;
    float* o = which ? t2 : t1;
    for (int co = threadIdx.x; co < 512; co += 256) {
      const float4* wr = (const float4*)(w + co * 512);
      float acc = bv[co];
#pragma unroll 8
      for (int k = 0; k < 128; ++k) {
        float4 wv = wr[k];
        acc += wv.x * s[4*k] + wv.y * s[4*k+1] + wv.z * s[4*k+2] + wv.w * s[4*k+3];
      }
      o[n * 512 + co] = LRELU(acc);
    }
  }
}

// ---------------- kB: dw2 matmul (on-the-fly im2col) + pk2/pb2 ----------------
// matmul part: grid 512 = kc(32: 16-ci chunks) x bo(8: 256-o2 tiles) x nh(2: n halves)
// thread = o2 in tile; owns 4 n, 9 p; acc[4][9]; LDS ht[4][16][20] broadcast-read
__global__ __launch_bounds__(256) void kB(const float* __restrict__ h2,
    const float* __restrict__ dw2_w,
    const float* __restrict__ t1, const float* __restrict__ t2,
    const float* __restrict__ pk2_w, const float* __restrict__ pk2_b,
    const float* __restrict__ pb2_w, const float* __restrict__ pb2_b,
    float* __restrict__ D, float* __restrict__ pk, float* __restrict__ pb) {
  __shared__ float smem[1280];
  int b = blockIdx.x;
  int tid = threadIdx.x;
  if (b < 512) {
    int kc = b & 31; int bt = b >> 5; int bo = bt & 7; int nh = bt >> 3;
    // stage ht[nn][ci16][pix] with row stride 20 (16B-aligned, 2-way max on write)
    {
      int pix = tid & 15; int ci4 = (tid >> 4) & 3; int nn = tid >> 6;
      const float* src = h2 + (nh * 4 + nn) * 8192 + pix * 512 + kc * 16 + ci4 * 4;
      float4 v = *(const float4*)src;
      float* dst = &smem[(nn * 16 + ci4 * 4) * 20 + pix];
      dst[0]  = v.x;
      dst[20] = v.y;
      dst[40] = v.z;
      dst[60] = v.w;
    }
    __syncthreads();
    int o2 = bo * 256 + tid;
    const float4* wr = (const float4*)(dw2_w + o2 * 2048 + kc * 64);
    float acc[4][9];
#pragma unroll
    for (int nn = 0; nn < 4; ++nn)
#pragma unroll
      for (int p = 0; p < 9; ++p) acc[nn][p] = 0.f;
    // r table: p -> top-left pix of its 2x2 window
    // p: 0 1 2 3 4 5 6 7 8 -> r: 0 1 2 4 5 6 8 9 10
    for (int ci = 0; ci < 16; ++ci) {
      float4 wv = wr[ci];  // 4 (ky,kx) weights for this ci
#pragma unroll
      for (int nn = 0; nn < 4; ++nn) {
        const float* hrow = &smem[(nn * 16 + ci) * 20];
        float4 a0 = *(const float4*)(hrow + 0);
        float4 a1 = *(const float4*)(hrow + 4);
        float4 a2 = *(const float4*)(hrow + 8);
        float4 a3 = *(const float4*)(hrow + 12);
        float vv[16];
        vv[0]=a0.x; vv[1]=a0.y; vv[2]=a0.z; vv[3]=a0.w;
        vv[4]=a1.x; vv[5]=a1.y; vv[6]=a1.z; vv[7]=a1.w;
        vv[8]=a2.x; vv[9]=a2.y; vv[10]=a2.z; vv[11]=a2.w;
        vv[12]=a3.x; vv[13]=a3.y; vv[14]=a3.z; vv[15]=a3.w;
#pragma unroll
        for (int p = 0; p < 9; ++p) {
          int r = (p / 3) * 4 + (p % 3);
          acc[nn][p] += wv.x * vv[r] + wv.y * vv[r + 1] + wv.z * vv[r + 4] + wv.w * vv[r + 5];
        }
      }
    }
#pragma unroll
    for (int nn = 0; nn < 4; ++nn)
#pragma unroll
      for (int p = 0; p < 9; ++p)
        atomicAdd(&D[((nh * 4 + nn) * 9 + p) * 2048 + o2], acc[nn][p]);
  } else {
    int idx = b - 512;  // 0..79
    int n = idx / 10; int tile = idx % 10;
    bool isPb = tile >= 8;
    float* s = smem;
    const float* src = (isPb ? t2 : t1) + n * 512;
    for (int i = tid; i < 512; i += 256) s[i] = src[i];
    __syncthreads();
    int o = (isPb ? tile - 8 : tile) * 256 + tid;
    const float* w = isPb ? pb2_w : pk2_w;
    float acc = (isPb ? pb2_b : pk2_b)[o];
    const float4* wr = (const float4*)(w + o * 512);
#pragma unroll 8
    for (int k = 0; k < 128; ++k) {
      float4 wv = wr[k];
      acc += wv.x * s[4*k] + wv.y * s[4*k+1] + wv.z * s[4*k+2] + wv.w * s[4*k+3];
    }
    if (isPb) pb[n * 512 + o] = acc; else pk[n * 2048 + o] = acc;
  }
}

// ---------------- kW: weff + pb -> wbuf[n][Q][160] ----------------
__global__ __launch_bounds__(256) void kW(const float* __restrict__ D,
    const float* __restrict__ pk, const float* __restrict__ dw2_b,
    const float* __restrict__ pb, float* __restrict__ wbuf) {
  int idx = blockIdx.x * 256 + threadIdx.x;
  if (idx >= 8 * 128 * 160) return;
  int t = idx % 160; int Qn = idx / 160; int Q = Qn & 127; int n = Qn >> 7;
  if (t >= 144) {
    wbuf[idx] = (t < 148) ? pb[n * 512 + Q * 4 + (t - 144)] : 0.f;
    return;
  }
  int o = t & 3; int u = t >> 2; int kx = u % 3; int v = u / 3;
  int i = v & 3; int ky = v >> 2; int p = ky * 3 + kx;
  const float* Dp  = D + (n * 9 + p) * 2048 + 16 * Q;
  const float* pkp = pk + n * 2048 + 16 * Q + 4 * o;
  const float* bp  = dw2_b + 16 * Q;
  float sum = 0.f;
#pragma unroll
  for (int j = 0; j < 4; ++j) sum += pkp[j] * (Dp[4 * j + i] + bp[4 * j + i]);
  wbuf[idx] = sum;
}

// ---------------- kC: fused grouped 3x3 conv, scalar-loaded weights ----------------
__global__ __launch_bounds__(256) void kC(const float* __restrict__ x,
    const float* __restrict__ wbuf, float* __restrict__ out) {
  int b = blockIdx.x; int rt = b & 3; int Q = (b >> 2) & 127; int n = b >> 9;
  __shared__ float xs[4][18][80];  // col = 4 + x; halos at col 3 (x=-1), 68 (x=64)
  const float* wb = wbuf + (size_t)(n * 128 + Q) * 160;  // block-uniform -> s_load
  const float* base = x + (size_t)(n * 512 + Q * 4) * 4096;
  for (int idx = threadIdx.x; idx < 1152; idx += 256) {
    int c4 = idx & 15; int rr = (idx >> 4) % 18; int ch = idx / 288;
    int gy = rt * 16 + rr - 1; gy = gy < 0 ? 1 : (gy > 63 ? 62 : gy);
    *(float4*)&xs[ch][rr][4 + 4 * c4] = *(const float4*)(base + ch * 4096 + gy * 64 + 4 * c4);
  }
  if (threadIdx.x < 144) {
    int idx = threadIdx.x;
    int side = idx & 1; int rr = (idx >> 1) % 18; int ch = idx / 36;
    int gy = rt * 16 + rr - 1; gy = gy < 0 ? 1 : (gy > 63 ? 62 : gy);
    xs[ch][rr][side ? 68 : 3] = base[ch * 4096 + gy * 64 + (side ? 62 : 1)];
  }
  __syncthreads();
  int r = threadIdx.x >> 4, e = threadIdx.x & 15;
  float acc[4][4];
#pragma unroll
  for (int o = 0; o < 4; ++o) {
    float bv = wb[144 + o];
#pragma unroll
    for (int px = 0; px < 4; ++px) acc[o][px] = bv;
  }
#pragma unroll
  for (int ky = 0; ky < 3; ++ky) {
#pragma unroll
    for (int i = 0; i < 4; ++i) {
      const float* rp = &xs[i][r + ky][4 * e];
      float4 v0 = *(const float4*)rp;
      float4 v1 = *(const float4*)(rp + 4);
      float2 v2 = *(const float2*)(rp + 8);
      float vv[10];
      vv[0]=v0.x; vv[1]=v0.y; vv[2]=v0.z; vv[3]=v0.w;
      vv[4]=v1.x; vv[5]=v1.y; vv[6]=v1.z; vv[7]=v1.w;
      vv[8]=v2.x; vv[9]=v2.y;
#pragma unroll
      for (int kx = 0; kx < 3; ++kx) {
        float w0 = wb[((ky * 4 + i) * 3 + kx) * 4 + 0];
        float w1 = wb[((ky * 4 + i) * 3 + kx) * 4 + 1];
        float w2 = wb[((ky * 4 + i) * 3 + kx) * 4 + 2];
        float w3 = wb[((ky * 4 + i) * 3 + kx) * 4 + 3];
#pragma unroll
        for (int px = 0; px < 4; ++px) {
          float xv = vv[3 + px + kx];
          acc[0][px] += w0 * xv;
          acc[1][px] += w1 * xv;
          acc[2][px] += w2 * xv;
          acc[3][px] += w3 * xv;
        }
      }
    }
  }
  int gy = rt * 16 + r;
#pragma unroll
  for (int o = 0; o < 4; ++o) {
    float4 st; st.x = acc[o][0]; st.y = acc[o][1]; st.z = acc[o][2]; st.w = acc[o][3];
    *(float4*)&out[(((size_t)(n * 512 + Q * 4 + o)) * 64 + gy) * 64 + 4 * e] = st;
  }
}

extern "C" void kernel_launch(void* const* d_in, const int* in_sizes, int n_in,
                              void* d_out, int out_size, void* d_ws, size_t ws_size,
                              hipStream_t stream) {
  const float* style = (const float*)d_in[0];
  const float* pred  = (const float*)d_in[1];
  const float* dw1_w = (const float*)d_in[2];
  const float* dw1_b = (const float*)d_in[3];
  const float* dw2_w = (const float*)d_in[4];
  const float* dw2_b = (const float*)d_in[5];
  const float* pk1_w = (const float*)d_in[6];
  const float* pk1_b = (const float*)d_in[7];
  const float* pk2_w = (const float*)d_in[8];
  const float* pk2_b = (const float*)d_in[9];
  const float* pb1_w = (const float*)d_in[10];
  const float* pb1_b = (const float*)d_in[11];
  const float* pb2_w = (const float*)d_in[12];
  const float* pb2_b = (const float*)d_in[13];
  float* ws = (float*)d_ws;
  float* h2 = ws + H2_OFF;
  float* t1 = ws + T1_OFF;
  float* t2 = ws + T2_OFF;
  float* pk = ws + PK_OFF;
  float* pb = ws + PB_OFF;
  float* D  = ws + D_OFF;
  float* wb = ws + WB_OFF;
  float* out = (float*)d_out;

  hipMemsetAsync(D, 0, (size_t)8 * 9 * 2048 * sizeof(float), stream);
  kA<<<272, 256, 0, stream>>>(style, dw1_w, dw1_b, pk1_w, pk1_b, pb1_w, pb1_b, h2, t1, t2);
  kB<<<592, 256, 0, stream>>>(h2, dw2_w, t1, t2, pk2_w, pk2_b, pb2_w, pb2_b, D, pk, pb);
  kW<<<640, 256, 0, stream>>>(D, pk, dw2_b, pb, wb);
  kC<<<4096, 256, 0, stream>>>(pred, wb, out);
}